// Round 1
// baseline (1474.493 us; speedup 1.0000x reference)
//
#include <hip/hip_runtime.h>
#include <math.h>

#define NH 16
#define DD 128
#define SS 2048
#define NB 2
#define NQ 7

struct cplx { float r, i; };
__device__ __forceinline__ cplx cmul(cplx a, cplx b){ cplx o; o.r = a.r*b.r - a.i*b.i; o.i = a.r*b.i + a.i*b.r; return o; }
__device__ __forceinline__ cplx cadd(cplx a, cplx b){ cplx o; o.r = a.r+b.r; o.i = a.i+b.i; return o; }

// ---------------- gates: composite Rz@Ry@Rx per (set,head,qubit) ----------------
__global__ void gates_kernel(const float* __restrict__ qp, const float* __restrict__ kp,
                             const float* __restrict__ vp, float* __restrict__ gates){
    int t = threadIdx.x;
    if (t >= 3*NH*NQ) return;
    int set = t / (NH*NQ);
    int rem = t % (NH*NQ);
    const float* p = (set==0 ? qp : (set==1 ? kp : vp)) + rem*3;
    float a = p[0]*0.5f, b = p[1]*0.5f, c = p[2]*0.5f;
    float ca=cosf(a), sa=sinf(a), cb=cosf(b), sb=sinf(b), cc=cosf(c), sc=sinf(c);
    cplx rx00={ca,0.f}, rx01={0.f,-sa}, rx10={0.f,-sa}, rx11={ca,0.f};
    cplx ry00={cb,0.f}, ry01={-sb,0.f}, ry10={sb,0.f}, ry11={cb,0.f};
    cplx e0={cc,-sc}, e1={cc,sc};
    cplx m00 = cadd(cmul(ry00,rx00), cmul(ry01,rx10));
    cplx m01 = cadd(cmul(ry00,rx01), cmul(ry01,rx11));
    cplx m10 = cadd(cmul(ry10,rx00), cmul(ry11,rx10));
    cplx m11 = cadd(cmul(ry10,rx01), cmul(ry11,rx11));
    cplx g00 = cmul(e0,m00), g01 = cmul(e0,m01), g10 = cmul(e1,m10), g11 = cmul(e1,m11);
    float* gp = gates + t*8;
    gp[0]=g00.r; gp[1]=g00.i; gp[2]=g01.r; gp[3]=g01.i;
    gp[4]=g10.r; gp[5]=g10.i; gp[6]=g11.r; gp[7]=g11.i;
}

// ---------------- qkv: butterfly transform, one wave per (token, head) ----------------
// lane holds psi[lane] (c0) and psi[lane+64] (c1). Stage q=0 (stride 64) is in-thread;
// stages 1..6 (stride 32..1) are shfl_xor exchanges.
__global__ __launch_bounds__(256) void qkv_kernel(const float* __restrict__ states,
                                                  const float* __restrict__ gates,
                                                  float* __restrict__ qb, float* __restrict__ kb,
                                                  float* __restrict__ vb){
    int wave = blockIdx.x*4 + (threadIdx.x >> 6);
    int lane = threadIdx.x & 63;
    int h = wave & 15;
    int token = wave >> 4;          // b*S + s
    int b = token >> 11, s = token & 2047;
    const float* xp = states + (size_t)token*2048 + h*128;
    float x0 = xp[lane], x1 = xp[lane+64];
    size_t obase = (((size_t)(b*16 + h))*2048 + s)*128;   // [B,H,S,D]
    float* outs[3];
    outs[0]=qb; outs[1]=kb; outs[2]=vb;
    for (int set=0; set<3; ++set){
        float c0r = x0, c0i = 0.f, c1r = x1, c1i = 0.f;
        const float* gp = gates + (size_t)(set*NH + h)*NQ*8;
        {   // stage q=0, stride 64: pair (lane, lane+64) both in-thread
            float g00r=gp[0],g00i=gp[1],g01r=gp[2],g01i=gp[3];
            float g10r=gp[4],g10i=gp[5],g11r=gp[6],g11i=gp[7];
            float n0r = g00r*c0r - g00i*c0i + g01r*c1r - g01i*c1i;
            float n0i = g00r*c0i + g00i*c0r + g01r*c1i + g01i*c1r;
            float n1r = g10r*c0r - g10i*c0i + g11r*c1r - g11i*c1i;
            float n1i = g10r*c0i + g10i*c0r + g11r*c1i + g11i*c1r;
            c0r=n0r; c0i=n0i; c1r=n1r; c1i=n1i;
        }
        #pragma unroll
        for (int q=1; q<7; ++q){
            const float* g = gp + q*8;
            float g00r=g[0],g00i=g[1],g01r=g[2],g01i=g[3];
            float g10r=g[4],g10i=g[5],g11r=g[6],g11i=g[7];
            int R = 64 >> q;
            bool hi = (lane & R) != 0;
            // if low half of pair: new = g00*self + g01*partner
            // if high half:        new = g11*self + g10*partner
            float ar = hi ? g11r : g00r, ai = hi ? g11i : g00i;
            float br = hi ? g10r : g01r, bi = hi ? g10i : g01i;
            float p0r = __shfl_xor(c0r, R), p0i = __shfl_xor(c0i, R);
            float p1r = __shfl_xor(c1r, R), p1i = __shfl_xor(c1i, R);
            float n0r = ar*c0r - ai*c0i + br*p0r - bi*p0i;
            float n0i = ar*c0i + ai*c0r + br*p0i + bi*p0r;
            float n1r = ar*c1r - ai*c1i + br*p1r - bi*p1i;
            float n1i = ar*c1i + ai*c1r + br*p1i + bi*p1r;
            c0r=n0r; c0i=n0i; c1r=n1r; c1i=n1i;
        }
        float* op = outs[set] + obase;
        op[lane]      = c0r*c0r + c0i*c0i;
        op[lane + 64] = c1r*c1r + c1i*c1i;
    }
}

// ---------------- flash attention, fp32 ----------------
#define QT 64
#define KT 32
__global__ __launch_bounds__(256) void flash_kernel(const float* __restrict__ qb,
                                                    const float* __restrict__ kb,
                                                    const float* __restrict__ vb,
                                                    const int* __restrict__ mask,
                                                    float* __restrict__ ctx){
    __shared__ float q_s[QT][132];
    __shared__ float k_s[KT][132];
    __shared__ float v_s[KT][128];
    __shared__ float s_s[QT][33];
    __shared__ float alpha_s[QT];
    __shared__ float l_s[QT];
    __shared__ float maskv[KT];
    int t = threadIdx.x;
    int bh = blockIdx.x >> 5;       // 0..31  (b*16+h)
    int qt = blockIdx.x & 31;
    int b  = bh >> 4;
    size_t base = (size_t)bh * SS * DD;
    // q tile -> LDS, pre-scaled by 1/sqrt(128)
    const float* qg = qb + base + (size_t)qt*QT*DD;
    const float sc = 0.08838834764831845f;
    #pragma unroll
    for (int i=0;i<8;++i){
        int lin = t*4 + i*1024;
        int r = lin >> 7, cidx = lin & 127;
        float4 vq = *(const float4*)(qg + lin);
        vq.x*=sc; vq.y*=sc; vq.z*=sc; vq.w*=sc;
        *(float4*)&q_s[r][cidx] = vq;
    }
    int tc = t & 15, tr = t >> 4;   // QK role: cols {tc, tc+16}, rows tr*4..+3
    int srow = t >> 2, sq = t & 3;  // softmax role: 4 lanes per row
    int dg = t & 15, rg = t >> 4;   // PV role: d in {dg*4..+3, 64+dg*4..+3}, rows rg*4..+3
    float m = -1e30f, l = 0.f;
    float O[4][8];
    #pragma unroll
    for (int i=0;i<4;++i){ O[i][0]=0;O[i][1]=0;O[i][2]=0;O[i][3]=0;O[i][4]=0;O[i][5]=0;O[i][6]=0;O[i][7]=0; }
    const int* mp = mask + b*SS;
    for (int kt=0; kt<SS/KT; ++kt){
        __syncthreads();   // protect s_s/v_s from previous PV
        const float* kg = kb + base + (size_t)kt*KT*DD;
        const float* vg = vb + base + (size_t)kt*KT*DD;
        #pragma unroll
        for (int i=0;i<4;++i){
            int lin = t*4 + i*1024;
            int r = lin >> 7, cidx = lin & 127;
            *(float4*)&k_s[r][cidx] = *(const float4*)(kg + lin);
            *(float4*)&v_s[r][cidx] = *(const float4*)(vg + lin);
        }
        if (t < KT) maskv[t] = (float)mp[kt*KT + t];
        __syncthreads();
        // ---- S = q k^T
        float acc[4][2];
        #pragma unroll
        for (int i=0;i<4;++i){ acc[i][0]=0.f; acc[i][1]=0.f; }
        #pragma unroll 4
        for (int d=0; d<DD; d+=4){
            float4 k0 = *(const float4*)&k_s[tc][d];
            float4 k1 = *(const float4*)&k_s[tc+16][d];
            #pragma unroll
            for (int i=0;i<4;++i){
                float4 qv = *(const float4*)&q_s[tr*4+i][d];
                acc[i][0] += qv.x*k0.x + qv.y*k0.y + qv.z*k0.z + qv.w*k0.w;
                acc[i][1] += qv.x*k1.x + qv.y*k1.y + qv.z*k1.z + qv.w*k1.w;
            }
        }
        #pragma unroll
        for (int i=0;i<4;++i){ s_s[tr*4+i][tc] = acc[i][0]; s_s[tr*4+i][tc+16] = acc[i][1]; }
        __syncthreads();
        // ---- online softmax (4 lanes cooperate per row)
        float sv[8]; float tmax = -1e30f;
        #pragma unroll
        for (int e=0;e<8;++e){
            int cidx = sq*8+e;
            float s0 = s_s[srow][cidx];
            if (maskv[cidx] == 0.f) s0 = -1e30f;
            sv[e] = s0; tmax = fmaxf(tmax, s0);
        }
        tmax = fmaxf(tmax, __shfl_xor(tmax,1));
        tmax = fmaxf(tmax, __shfl_xor(tmax,2));
        float m_new = fmaxf(m, tmax);
        float alpha = __expf(m - m_new);
        float rsum = 0.f;
        #pragma unroll
        for (int e=0;e<8;++e){
            float pv = __expf(sv[e]-m_new);
            rsum += pv;
            s_s[srow][sq*8+e] = pv;
        }
        rsum += __shfl_xor(rsum,1);
        rsum += __shfl_xor(rsum,2);
        l = l*alpha + rsum;
        m = m_new;
        if (sq==0) alpha_s[srow] = alpha;
        __syncthreads();
        // ---- O = O*alpha + P V
        float al[4];
        #pragma unroll
        for (int rr=0;rr<4;++rr) al[rr] = alpha_s[rg*4+rr];
        #pragma unroll
        for (int rr=0;rr<4;++rr){
            #pragma unroll
            for (int jj=0;jj<8;++jj) O[rr][jj] *= al[rr];
        }
        #pragma unroll 4
        for (int k2=0;k2<KT;++k2){
            float4 va  = *(const float4*)&v_s[k2][dg*4];
            float4 vb4 = *(const float4*)&v_s[k2][64 + dg*4];
            #pragma unroll
            for (int rr=0;rr<4;++rr){
                float pv = s_s[rg*4+rr][k2];
                O[rr][0] += pv*va.x;  O[rr][1] += pv*va.y;  O[rr][2] += pv*va.z;  O[rr][3] += pv*va.w;
                O[rr][4] += pv*vb4.x; O[rr][5] += pv*vb4.y; O[rr][6] += pv*vb4.z; O[rr][7] += pv*vb4.w;
            }
        }
    }
    __syncthreads();
    if (sq==0) l_s[srow] = l;
    __syncthreads();
    int hloc = bh & 15;
    #pragma unroll
    for (int rr=0;rr<4;++rr){
        int srow_g = qt*QT + rg*4 + rr;
        float inv = 1.f / l_s[rg*4+rr];
        float* op = ctx + (((size_t)(b*SS + srow_g))*NH + hloc)*DD;   // [B,S,H,D] = concat layout
        float4 o1, o2;
        o1.x=O[rr][0]*inv; o1.y=O[rr][1]*inv; o1.z=O[rr][2]*inv; o1.w=O[rr][3]*inv;
        o2.x=O[rr][4]*inv; o2.y=O[rr][5]*inv; o2.z=O[rr][6]*inv; o2.w=O[rr][7]*inv;
        *(float4*)(op + dg*4)      = o1;
        *(float4*)(op + 64 + dg*4) = o2;
    }
}

// ---------------- projection: out[t,j] = b[j] + sum_f ctx[t,f] W[j,f] ----------------
__global__ __launch_bounds__(256) void proj_kernel(const float* __restrict__ ctx,
                                                   const float* __restrict__ W,
                                                   const float* __restrict__ bo,
                                                   float* __restrict__ out){
    __shared__ float a_s[32][36];
    __shared__ float w_s[128][36];
    int t = threadIdx.x;
    int rowbase = blockIdx.x * 32;
    int r0 = (t >> 4) * 2;
    int j0 = t & 15;               // cols j0 + 16*jj
    float acc[2][8];
    #pragma unroll
    for (int rr=0;rr<2;++rr){ acc[rr][0]=0;acc[rr][1]=0;acc[rr][2]=0;acc[rr][3]=0;acc[rr][4]=0;acc[rr][5]=0;acc[rr][6]=0;acc[rr][7]=0; }
    for (int ft=0; ft<2048; ft+=32){
        __syncthreads();
        {
            int r = t >> 3, f0 = (t & 7) * 4;
            *(float4*)&a_s[r][f0] = *(const float4*)(ctx + (size_t)(rowbase + r)*2048 + ft + f0);
        }
        {
            int j = t >> 1, f0 = (t & 1) * 16;
            const float* wp = W + (size_t)j*2048 + ft + f0;
            #pragma unroll
            for (int i=0;i<4;++i)
                *(float4*)&w_s[j][f0 + i*4] = *(const float4*)(wp + i*4);
        }
        __syncthreads();
        #pragma unroll 8
        for (int f=0; f<32; ++f){
            float a0 = a_s[r0][f], a1 = a_s[r0+1][f];
            #pragma unroll
            for (int jj=0;jj<8;++jj){
                float w = w_s[j0 + 16*jj][f];
                acc[0][jj] += a0*w;
                acc[1][jj] += a1*w;
            }
        }
    }
    #pragma unroll
    for (int rr=0;rr<2;++rr){
        float* op = out + (size_t)(rowbase + r0 + rr)*128;
        #pragma unroll
        for (int jj=0;jj<8;++jj){
            int j = j0 + 16*jj;
            op[j] = acc[rr][jj] + bo[j];
        }
    }
}

extern "C" void kernel_launch(void* const* d_in, const int* in_sizes, int n_in,
                              void* d_out, int out_size, void* d_ws, size_t ws_size,
                              hipStream_t stream){
    const float* states = (const float*)d_in[0];
    const int*   mask   = (const int*)d_in[1];
    const float* qp     = (const float*)d_in[2];
    const float* kp     = (const float*)d_in[3];
    const float* vp     = (const float*)d_in[4];
    const float* W      = (const float*)d_in[5];
    const float* bo     = (const float*)d_in[6];
    float* out = (float*)d_out;
    float* ws  = (float*)d_ws;
    // workspace layout (floats): gates (4096) | q | k | v | ctx  (each 8388608)
    float* gates = ws;
    float* qb  = ws + 4096;
    float* kb  = qb + 8388608;
    float* vb  = kb + 8388608;
    float* ctx = vb + 8388608;
    hipLaunchKernelGGL(gates_kernel, dim3(1), dim3(384), 0, stream, qp, kp, vp, gates);
    hipLaunchKernelGGL(qkv_kernel, dim3(16384), dim3(256), 0, stream, states, gates, qb, kb, vb);
    hipLaunchKernelGGL(flash_kernel, dim3(1024), dim3(256), 0, stream, qb, kb, vb, mask, ctx);
    hipLaunchKernelGGL(proj_kernel, dim3(128), dim3(256), 0, stream, ctx, W, bo, out);
}

// Round 2
// 414.033 us; speedup vs baseline: 3.5613x; 3.5613x over previous
//
#include <hip/hip_runtime.h>
#include <math.h>

#define NH 16
#define DD 128
#define SS 2048
#define NQ 7

typedef __attribute__((ext_vector_type(8))) short bf16x8;
typedef __attribute__((ext_vector_type(16))) float f32x16;

#define MFMA32(a,b,c) __builtin_amdgcn_mfma_f32_32x32x16_bf16(a,b,c,0,0,0)

__device__ __forceinline__ ushort f2b(float x){
    unsigned u = __float_as_uint(x); u += 0x7FFF + ((u>>16)&1); return (ushort)(u>>16);
}
__device__ __forceinline__ unsigned pkbf(float a, float b){
    unsigned ua = __float_as_uint(a); ua += 0x7FFF + ((ua>>16)&1);
    unsigned ub = __float_as_uint(b); ub += 0x7FFF + ((ub>>16)&1);
    return (ua>>16) | (ub & 0xFFFF0000u);
}

struct cplx { float r, i; };
__device__ __forceinline__ cplx cmul(cplx a, cplx b){ cplx o; o.r = a.r*b.r - a.i*b.i; o.i = a.r*b.i + a.i*b.r; return o; }
__device__ __forceinline__ cplx cadd(cplx a, cplx b){ cplx o; o.r = a.r+b.r; o.i = a.i+b.i; return o; }

// ---------------- gates ----------------
__global__ void gates_kernel(const float* __restrict__ qp, const float* __restrict__ kp,
                             const float* __restrict__ vp, float* __restrict__ gates){
    int t = threadIdx.x;
    if (t >= 3*NH*NQ) return;
    int set = t / (NH*NQ);
    int rem = t % (NH*NQ);
    const float* p = (set==0 ? qp : (set==1 ? kp : vp)) + rem*3;
    float a = p[0]*0.5f, b = p[1]*0.5f, c = p[2]*0.5f;
    float ca=cosf(a), sa=sinf(a), cb=cosf(b), sb=sinf(b), cc=cosf(c), sc=sinf(c);
    cplx rx00={ca,0.f}, rx01={0.f,-sa}, rx10={0.f,-sa}, rx11={ca,0.f};
    cplx ry00={cb,0.f}, ry01={-sb,0.f}, ry10={sb,0.f}, ry11={cb,0.f};
    cplx e0={cc,-sc}, e1={cc,sc};
    cplx m00 = cadd(cmul(ry00,rx00), cmul(ry01,rx10));
    cplx m01 = cadd(cmul(ry00,rx01), cmul(ry01,rx11));
    cplx m10 = cadd(cmul(ry10,rx00), cmul(ry11,rx10));
    cplx m11 = cadd(cmul(ry10,rx01), cmul(ry11,rx11));
    cplx g00 = cmul(e0,m00), g01 = cmul(e0,m01), g10 = cmul(e1,m10), g11 = cmul(e1,m11);
    float* gp = gates + t*8;
    gp[0]=g00.r; gp[1]=g00.i; gp[2]=g01.r; gp[3]=g01.i;
    gp[4]=g10.r; gp[5]=g10.i; gp[6]=g11.r; gp[7]=g11.i;
}

// ---------------- qkv: butterfly transform -> bf16 Q (prescaled), K, V^T ----------------
// Block: one (b,h) x 64-token tile; wave w handles 16 tokens serially.
__global__ __launch_bounds__(256) void qkv_kernel(const float* __restrict__ states,
        const float* __restrict__ gates, ushort* __restrict__ qb,
        ushort* __restrict__ kb, ushort* __restrict__ vt){
    int t = threadIdx.x, w = t >> 6, lane = t & 63;
    int bh = blockIdx.x >> 5, st = blockIdx.x & 31;
    int b = bh >> 4, h = bh & 15;
    const float sc = 0.08838834764831845f;   // 1/sqrt(128)
    for (int i=0; i<16; ++i){
        int s = st*64 + w*16 + i;
        const float* xp = states + ((size_t)(b*SS + s))*2048 + h*128;
        float x0 = xp[lane], x1 = xp[lane+64];
        #pragma unroll
        for (int set=0; set<3; ++set){
            float c0r = x0, c0i = 0.f, c1r = x1, c1i = 0.f;
            const float* gp = gates + (size_t)(set*NH + h)*NQ*8;
            {   // stage q=0, stride 64: in-thread
                float g00r=gp[0],g00i=gp[1],g01r=gp[2],g01i=gp[3];
                float g10r=gp[4],g10i=gp[5],g11r=gp[6],g11i=gp[7];
                float n0r = g00r*c0r - g00i*c0i + g01r*c1r - g01i*c1i;
                float n0i = g00r*c0i + g00i*c0r + g01r*c1i + g01i*c1r;
                float n1r = g10r*c0r - g10i*c0i + g11r*c1r - g11i*c1i;
                float n1i = g10r*c0i + g10i*c0r + g11r*c1i + g11i*c1r;
                c0r=n0r; c0i=n0i; c1r=n1r; c1i=n1i;
            }
            #pragma unroll
            for (int q=1; q<7; ++q){
                const float* g = gp + q*8;
                float g00r=g[0],g00i=g[1],g01r=g[2],g01i=g[3];
                float g10r=g[4],g10i=g[5],g11r=g[6],g11i=g[7];
                int R = 64 >> q;
                bool hi2 = (lane & R) != 0;
                float ar = hi2 ? g11r : g00r, ai = hi2 ? g11i : g00i;
                float br = hi2 ? g10r : g01r, bi = hi2 ? g10i : g01i;
                float p0r = __shfl_xor(c0r, R), p0i = __shfl_xor(c0i, R);
                float p1r = __shfl_xor(c1r, R), p1i = __shfl_xor(c1i, R);
                float n0r = ar*c0r - ai*c0i + br*p0r - bi*p0i;
                float n0i = ar*c0i + ai*c0r + br*p0i + bi*p0r;
                float n1r = ar*c1r - ai*c1i + br*p1r - bi*p1i;
                float n1i = ar*c1i + ai*c1r + br*p1i + bi*p1r;
                c0r=n0r; c0i=n0i; c1r=n1r; c1i=n1i;
            }
            float p0 = c0r*c0r + c0i*c0i, p1 = c1r*c1r + c1i*c1i;
            if (set == 0){
                ushort* op = qb + ((size_t)bh*SS + s)*128;
                op[lane] = f2b(p0*sc); op[lane+64] = f2b(p1*sc);
            } else if (set == 1){
                ushort* op = kb + ((size_t)bh*SS + s)*128;
                op[lane] = f2b(p0); op[lane+64] = f2b(p1);
            } else {
                vt[((size_t)bh*128 + lane)*SS + s]      = f2b(p0);   // [bh][d][s], L2-merged
                vt[((size_t)bh*128 + 64 + lane)*SS + s] = f2b(p1);
            }
        }
    }
}

// ---------------- flash attention, bf16 MFMA (32x32x16) ----------------
// WG = 4 waves x 32 q = 128 q.  Sᵀ = K·Qᵀ (C cols = q), P stays in registers.
__global__ __launch_bounds__(256, 2) void flash_kernel(
        const ushort* __restrict__ qb, const ushort* __restrict__ kb,
        const ushort* __restrict__ vt, const int* __restrict__ mask,
        float* __restrict__ ctx){
    __shared__ __align__(16) char smem[35840];
    ushort* Qs = (ushort*)smem;            // [128][136]   (staging, aliases Kt/Vt)
    ushort* Kt = (ushort*)smem;            // [64][136]
    ushort* Vt = (ushort*)(smem + 17408);  // [128][72]    V^T tile
    int t = threadIdx.x;
    int lane = t & 63, w = t >> 6;
    int hi = lane >> 5, ln = lane & 31;
    int bh = blockIdx.x >> 4, qt = blockIdx.x & 15;
    int b = bh >> 4;
    size_t hb = (size_t)bh * (SS*128);
    // ---- stage Q tile (128x128 bf16) coalesced, then pull B-fragments to regs
    {
        const ushort* src = qb + hb + (size_t)qt*(128*128) + (t>>1)*128 + (t&1)*64;
        ushort* dst = Qs + (t>>1)*136 + (t&1)*64;
        #pragma unroll
        for (int i=0;i<8;++i) *(int4*)(dst + i*8) = *(const int4*)(src + i*8);
    }
    __syncthreads();
    bf16x8 qf[8];
    #pragma unroll
    for (int ds=0; ds<8; ++ds)
        qf[ds] = *(const bf16x8*)(Qs + (w*32 + ln)*136 + ds*16 + hi*8);
    f32x16 O[4];
    #pragma unroll
    for (int d=0; d<4; ++d){
        #pragma unroll
        for (int r=0;r<16;++r) O[d][r] = 0.f;
    }
    float m = -1e30f, l = 0.f;
    const ushort* kg = kb + hb;
    const ushort* vg = vt + hb;
    const int* mp = mask + b*SS;
    for (int kt=0; kt<SS/64; ++kt){
        __syncthreads();
        {   // K tile: 64 keys x 128 d
            int row = t >> 2, sg2 = (t & 3)*32;
            const ushort* src = kg + (size_t)(kt*64 + row)*128 + sg2;
            ushort* dst = Kt + row*136 + sg2;
            #pragma unroll
            for (int i=0;i<4;++i) *(int4*)(dst + i*8) = *(const int4*)(src + i*8);
        }
        {   // V^T tile: 128 d x 64 k
            int row = t >> 1, sg2 = (t & 1)*32;
            const ushort* src = vg + (size_t)row*SS + kt*64 + sg2;
            ushort* dst = Vt + row*72 + sg2;
            #pragma unroll
            for (int i=0;i<4;++i) *(int4*)(dst + i*8) = *(const int4*)(src + i*8);
        }
        int mk = mp[kt*64 + lane];
        __syncthreads();
        // ---- S^T = K · Q~^T   (rows = keys, cols = q)
        f32x16 S0, S1;
        #pragma unroll
        for (int r=0;r<16;++r){ S0[r]=0.f; S1[r]=0.f; }
        #pragma unroll
        for (int ds=0; ds<8; ++ds){
            bf16x8 k0 = *(const bf16x8*)(Kt + ln*136 + ds*16 + hi*8);
            bf16x8 k1 = *(const bf16x8*)(Kt + (32+ln)*136 + ds*16 + hi*8);
            S0 = MFMA32(k0, qf[ds], S0);
            S1 = MFMA32(k1, qf[ds], S1);
        }
        // ---- mask (fast path: all ones)
        unsigned long long bal = __ballot(mk != 0);
        if (bal != ~0ull){
            #pragma unroll
            for (int r=0;r<16;++r){
                int row0 = ((r>>2)<<3) + (hi<<2) + (r&3);
                if (__shfl(mk, row0) == 0)      S0[r] = -1e30f;
                if (__shfl(mk, 32 + row0) == 0) S1[r] = -1e30f;
            }
        }
        // ---- online softmax (per-lane col q; one shfl to merge hi halves)
        float rmax = -1e30f;
        #pragma unroll
        for (int r=0;r<16;++r){ rmax = fmaxf(rmax, S0[r]); rmax = fmaxf(rmax, S1[r]); }
        rmax = fmaxf(rmax, __shfl_xor(rmax, 32));
        float mn = fmaxf(fmaxf(m, rmax), -1e20f);
        float alpha = __expf(m - mn);
        float rs = 0.f;
        #pragma unroll
        for (int r=0;r<16;++r){
            S0[r] = __expf(S0[r] - mn); rs += S0[r];
            S1[r] = __expf(S1[r] - mn); rs += S1[r];
        }
        rs += __shfl_xor(rs, 32);
        l = l*alpha + rs; m = mn;
        if (__ballot(alpha == 1.0f) != ~0ull){
            #pragma unroll
            for (int d=0; d<4; ++d){
                #pragma unroll
                for (int r=0;r<16;++r) O[d][r] *= alpha;
            }
        }
        // ---- O^T += V^T · P  (P B-fragments built in-register from S^T C-layout)
        #pragma unroll
        for (int m2=0; m2<2; ++m2){
            #pragma unroll
            for (int T=0; T<2; ++T){
                const f32x16& P = m2 ? S1 : S0;
                unsigned A0 = pkbf(P[8*T+0], P[8*T+1]);
                unsigned A1 = pkbf(P[8*T+2], P[8*T+3]);
                unsigned B0 = pkbf(P[8*T+4], P[8*T+5]);
                unsigned B1 = pkbf(P[8*T+6], P[8*T+7]);
                unsigned X0 = hi ? A0 : B0, X1 = hi ? A1 : B1;
                unsigned Y0 = (unsigned)__shfl_xor((int)X0, 32);
                unsigned Y1 = (unsigned)__shfl_xor((int)X1, 32);
                union { bf16x8 v; unsigned u[4]; } pf;
                pf.u[0] = hi ? Y0 : A0;
                pf.u[1] = hi ? Y1 : A1;
                pf.u[2] = hi ? B0 : Y0;
                pf.u[3] = hi ? B1 : Y1;
                int kc0 = m2*32 + T*16 + hi*8;
                #pragma unroll
                for (int db=0; db<4; ++db){
                    bf16x8 vf = *(const bf16x8*)(Vt + (db*32 + ln)*72 + kc0);
                    O[db] = MFMA32(vf, pf.v, O[db]);
                }
            }
        }
    }
    // ---- epilogue: normalize, store ctx [B,S,H*D] fp32
    float inv = 1.f / l;
    int sg = qt*128 + w*32 + ln;
    float* op = ctx + ((size_t)(b*SS + sg))*2048 + (bh & 15)*128;
    #pragma unroll
    for (int db=0; db<4; ++db){
        #pragma unroll
        for (int rq=0; rq<4; ++rq){
            float4 o;
            o.x = O[db][4*rq+0]*inv; o.y = O[db][4*rq+1]*inv;
            o.z = O[db][4*rq+2]*inv; o.w = O[db][4*rq+3]*inv;
            *(float4*)(op + db*32 + rq*8 + hi*4) = o;
        }
    }
}

// ---------------- projection (fp32) ----------------
__global__ __launch_bounds__(256) void proj_kernel(const float* __restrict__ ctx,
                                                   const float* __restrict__ W,
                                                   const float* __restrict__ bo,
                                                   float* __restrict__ out){
    __shared__ float a_s[32][36];
    __shared__ float w_s[128][36];
    int t = threadIdx.x;
    int rowbase = blockIdx.x * 32;
    int r0 = (t >> 4) * 2;
    int j0 = t & 15;
    float acc[2][8];
    #pragma unroll
    for (int rr=0;rr<2;++rr){ acc[rr][0]=0;acc[rr][1]=0;acc[rr][2]=0;acc[rr][3]=0;acc[rr][4]=0;acc[rr][5]=0;acc[rr][6]=0;acc[rr][7]=0; }
    for (int ft=0; ft<2048; ft+=32){
        __syncthreads();
        {
            int r = t >> 3, f0 = (t & 7) * 4;
            *(float4*)&a_s[r][f0] = *(const float4*)(ctx + (size_t)(rowbase + r)*2048 + ft + f0);
        }
        {
            int j = t >> 1, f0 = (t & 1) * 16;
            const float* wp = W + (size_t)j*2048 + ft + f0;
            #pragma unroll
            for (int i=0;i<4;++i)
                *(float4*)&w_s[j][f0 + i*4] = *(const float4*)(wp + i*4);
        }
        __syncthreads();
        #pragma unroll 8
        for (int f=0; f<32; ++f){
            float a0 = a_s[r0][f], a1 = a_s[r0+1][f];
            #pragma unroll
            for (int jj=0;jj<8;++jj){
                float ww = w_s[j0 + 16*jj][f];
                acc[0][jj] += a0*ww;
                acc[1][jj] += a1*ww;
            }
        }
    }
    #pragma unroll
    for (int rr=0;rr<2;++rr){
        float* op = out + (size_t)(rowbase + r0 + rr)*128;
        #pragma unroll
        for (int jj=0;jj<8;++jj){
            int j = j0 + 16*jj;
            op[j] = acc[rr][jj] + bo[j];
        }
    }
}

extern "C" void kernel_launch(void* const* d_in, const int* in_sizes, int n_in,
                              void* d_out, int out_size, void* d_ws, size_t ws_size,
                              hipStream_t stream){
    const float* states = (const float*)d_in[0];
    const int*   mask   = (const int*)d_in[1];
    const float* qp     = (const float*)d_in[2];
    const float* kp     = (const float*)d_in[3];
    const float* vp     = (const float*)d_in[4];
    const float* W      = (const float*)d_in[5];
    const float* bo     = (const float*)d_in[6];
    float* out = (float*)d_out;
    char* wsb = (char*)d_ws;
    // ws layout (bytes): gates f32[4096] | qb u16[8.4M] | kb u16 | vt u16 | ctx f32[8.4M]
    float*  gates = (float*)wsb;
    ushort* qb  = (ushort*)(wsb + 16384);
    ushort* kb  = (ushort*)(wsb + 16384 + 1*16777216);
    ushort* vtb = (ushort*)(wsb + 16384 + 2*16777216);
    float*  ctx = (float*) (wsb + 16384 + 3*16777216);
    hipLaunchKernelGGL(gates_kernel, dim3(1), dim3(384), 0, stream, qp, kp, vp, gates);
    hipLaunchKernelGGL(qkv_kernel, dim3(1024), dim3(256), 0, stream, states, gates, qb, kb, vtb);
    hipLaunchKernelGGL(flash_kernel, dim3(512), dim3(256), 0, stream, qb, kb, vtb, mask, ctx);
    hipLaunchKernelGGL(proj_kernel, dim3(128), dim3(256), 0, stream, ctx, W, bo, out);
}

// Round 3
// 254.816 us; speedup vs baseline: 5.7865x; 1.6248x over previous
//
#include <hip/hip_runtime.h>
#include <math.h>

#define NH 16
#define DD 128
#define SS 2048
#define NQ 7

typedef __attribute__((ext_vector_type(8))) short bf16x8;
typedef __attribute__((ext_vector_type(16))) float f32x16;

#define MFMA32(a,b,c) __builtin_amdgcn_mfma_f32_32x32x16_bf16(a,b,c,0,0,0)

__device__ __forceinline__ ushort f2b(float x){
    unsigned u = __float_as_uint(x); u += 0x7FFF + ((u>>16)&1); return (ushort)(u>>16);
}
__device__ __forceinline__ unsigned pkbf(float a, float b){
    unsigned ua = __float_as_uint(a); ua += 0x7FFF + ((ua>>16)&1);
    unsigned ub = __float_as_uint(b); ub += 0x7FFF + ((ub>>16)&1);
    return (ua>>16) | (ub & 0xFFFF0000u);
}

struct cplx { float r, i; };
__device__ __forceinline__ cplx cmul(cplx a, cplx b){ cplx o; o.r = a.r*b.r - a.i*b.i; o.i = a.r*b.i + a.i*b.r; return o; }
__device__ __forceinline__ cplx cadd(cplx a, cplx b){ cplx o; o.r = a.r+b.r; o.i = a.i+b.i; return o; }

// ---------------- prep: W -> B-fragment-major bf16 (blocks 0..127), gates (block 128) ----------------
__global__ __launch_bounds__(256) void prep_kernel(const float* __restrict__ qp, const float* __restrict__ kp,
                             const float* __restrict__ vp, const float* __restrict__ W,
                             float* __restrict__ gates, ushort* __restrict__ wfrag){
    int t = threadIdx.x;
    if (blockIdx.x < 128){
        // Wfrag[ct][ds][hi][ln][8]: element j = W[ct*32+ln][ds*16+hi*8+j]
        int tid = blockIdx.x*256 + t;        // 0..32767
        int ln = tid & 31, hi = (tid>>5)&1, ds = (tid>>6)&127, ct = tid>>13;
        int n = ct*32 + ln;
        const float* src = W + (size_t)n*2048 + ds*16 + hi*8;
        float4 f0 = *(const float4*)(src);
        float4 f1 = *(const float4*)(src + 4);
        int4 o;
        o.x = (int)pkbf(f0.x, f0.y); o.y = (int)pkbf(f0.z, f0.w);
        o.z = (int)pkbf(f1.x, f1.y); o.w = (int)pkbf(f1.z, f1.w);
        ((int4*)wfrag)[tid] = o;
        return;
    }
    // gates
    for (int it = t; it < 3*NH*NQ; it += 256){
        int set = it / (NH*NQ);
        int rem = it % (NH*NQ);
        const float* p = (set==0 ? qp : (set==1 ? kp : vp)) + rem*3;
        float a = p[0]*0.5f, b = p[1]*0.5f, c = p[2]*0.5f;
        float ca=cosf(a), sa=sinf(a), cb=cosf(b), sb=sinf(b), cc=cosf(c), sc=sinf(c);
        cplx rx00={ca,0.f}, rx01={0.f,-sa}, rx10={0.f,-sa}, rx11={ca,0.f};
        cplx ry00={cb,0.f}, ry01={-sb,0.f}, ry10={sb,0.f}, ry11={cb,0.f};
        cplx e0={cc,-sc}, e1={cc,sc};
        cplx m00 = cadd(cmul(ry00,rx00), cmul(ry01,rx10));
        cplx m01 = cadd(cmul(ry00,rx01), cmul(ry01,rx11));
        cplx m10 = cadd(cmul(ry10,rx00), cmul(ry11,rx10));
        cplx m11 = cadd(cmul(ry10,rx01), cmul(ry11,rx11));
        cplx g00 = cmul(e0,m00), g01 = cmul(e0,m01), g10 = cmul(e1,m10), g11 = cmul(e1,m11);
        float* gp = gates + it*8;
        gp[0]=g00.r; gp[1]=g00.i; gp[2]=g01.r; gp[3]=g01.i;
        gp[4]=g10.r; gp[5]=g10.i; gp[6]=g11.r; gp[7]=g11.i;
    }
}

// ---------------- qkv: butterfly -> bf16 Q (prescaled), K, V^T (via LDS transpose) ----------------
__global__ __launch_bounds__(256) void qkv_kernel(const float* __restrict__ states,
        const float* __restrict__ gates, ushort* __restrict__ qb,
        ushort* __restrict__ kb, ushort* __restrict__ vt){
    __shared__ ushort vs[128][66];     // [d][s_local], pad 66: d*33%32=d%32 -> conflict-free writes
    int t = threadIdx.x, w = t >> 6, lane = t & 63;
    int bh = blockIdx.x >> 5, st = blockIdx.x & 31;
    int b = bh >> 4, h = bh & 15;
    const float sc = 0.08838834764831845f;   // 1/sqrt(128)
    for (int i=0; i<16; ++i){
        int sl = w*16 + i;
        int s = st*64 + sl;
        const float* xp = states + ((size_t)(b*SS + s))*2048 + h*128;
        float x0 = xp[lane], x1 = xp[lane+64];
        #pragma unroll
        for (int set=0; set<3; ++set){
            float c0r = x0, c0i = 0.f, c1r = x1, c1i = 0.f;
            const float* gp = gates + (size_t)(set*NH + h)*NQ*8;
            {   // stage q=0, stride 64: in-thread
                float g00r=gp[0],g00i=gp[1],g01r=gp[2],g01i=gp[3];
                float g10r=gp[4],g10i=gp[5],g11r=gp[6],g11i=gp[7];
                float n0r = g00r*c0r - g00i*c0i + g01r*c1r - g01i*c1i;
                float n0i = g00r*c0i + g00i*c0r + g01r*c1i + g01i*c1r;
                float n1r = g10r*c0r - g10i*c0i + g11r*c1r - g11i*c1i;
                float n1i = g10r*c0i + g10i*c0r + g11r*c1i + g11i*c1r;
                c0r=n0r; c0i=n0i; c1r=n1r; c1i=n1i;
            }
            #pragma unroll
            for (int q=1; q<7; ++q){
                const float* g = gp + q*8;
                float g00r=g[0],g00i=g[1],g01r=g[2],g01i=g[3];
                float g10r=g[4],g10i=g[5],g11r=g[6],g11i=g[7];
                int R = 64 >> q;
                bool hi2 = (lane & R) != 0;
                float ar = hi2 ? g11r : g00r, ai = hi2 ? g11i : g00i;
                float br = hi2 ? g10r : g01r, bi = hi2 ? g10i : g01i;
                float p0r = __shfl_xor(c0r, R), p0i = __shfl_xor(c0i, R);
                float p1r = __shfl_xor(c1r, R), p1i = __shfl_xor(c1i, R);
                float n0r = ar*c0r - ai*c0i + br*p0r - bi*p0i;
                float n0i = ar*c0i + ai*c0r + br*p0i + bi*p0r;
                float n1r = ar*c1r - ai*c1i + br*p1r - bi*p1i;
                float n1i = ar*c1i + ai*c1r + br*p1i + bi*p1r;
                c0r=n0r; c0i=n0i; c1r=n1r; c1i=n1i;
            }
            float p0 = c0r*c0r + c0i*c0i, p1 = c1r*c1r + c1i*c1i;
            if (set == 0){
                ushort* op = qb + ((size_t)bh*SS + s)*128;
                op[lane] = f2b(p0*sc); op[lane+64] = f2b(p1*sc);
            } else if (set == 1){
                ushort* op = kb + ((size_t)bh*SS + s)*128;
                op[lane] = f2b(p0); op[lane+64] = f2b(p1);
            } else {
                vs[lane][sl]      = f2b(p0);
                vs[lane+64][sl]   = f2b(p1);
            }
        }
    }
    __syncthreads();
    // transposed coalesced store: vt[bh][d][s]
    {
        int row = t >> 1, half = t & 1;
        const ushort* src = &vs[row][half*32];
        ushort* dst = vt + ((size_t)bh*128 + row)*SS + st*64 + half*32;
        #pragma unroll
        for (int i4=0; i4<4; ++i4){
            union { int4 v; ushort2 e[4]; } u;
            u.e[0] = *(const ushort2*)(src + i4*8 + 0);
            u.e[1] = *(const ushort2*)(src + i4*8 + 2);
            u.e[2] = *(const ushort2*)(src + i4*8 + 4);
            u.e[3] = *(const ushort2*)(src + i4*8 + 6);
            *(int4*)(dst + i4*8) = u.v;
        }
    }
}

// ---------------- flash attention, bf16 MFMA; ctx out in A-fragment-major bf16 ----------------
__global__ __launch_bounds__(256, 2) void flash_kernel(
        const ushort* __restrict__ qb, const ushort* __restrict__ kb,
        const ushort* __restrict__ vt, const int* __restrict__ mask,
        ushort* __restrict__ ctxf){
    __shared__ __align__(16) char smem[35840];
    ushort* Qs = (ushort*)smem;            // [128][136]   (staging, aliases Kt/Vt)
    ushort* Kt = (ushort*)smem;            // [64][136]
    ushort* Vt = (ushort*)(smem + 17408);  // [128][72]    V^T tile
    int t = threadIdx.x;
    int lane = t & 63, w = t >> 6;
    int hi = lane >> 5, ln = lane & 31;
    int bh = blockIdx.x >> 4, qt = blockIdx.x & 15;
    int b = bh >> 4;
    size_t hb = (size_t)bh * (SS*128);
    {
        const ushort* src = qb + hb + (size_t)qt*(128*128) + (t>>1)*128 + (t&1)*64;
        ushort* dst = Qs + (t>>1)*136 + (t&1)*64;
        #pragma unroll
        for (int i=0;i<8;++i) *(int4*)(dst + i*8) = *(const int4*)(src + i*8);
    }
    __syncthreads();
    bf16x8 qf[8];
    #pragma unroll
    for (int ds=0; ds<8; ++ds)
        qf[ds] = *(const bf16x8*)(Qs + (w*32 + ln)*136 + ds*16 + hi*8);
    f32x16 O[4];
    #pragma unroll
    for (int d=0; d<4; ++d){
        #pragma unroll
        for (int r=0;r<16;++r) O[d][r] = 0.f;
    }
    float m = -1e30f, l = 0.f;
    const ushort* kg = kb + hb;
    const ushort* vg = vt + hb;
    const int* mp = mask + b*SS;
    for (int kt=0; kt<SS/64; ++kt){
        __syncthreads();
        {   // K tile: 64 keys x 128 d
            int row = t >> 2, sg2 = (t & 3)*32;
            const ushort* src = kg + (size_t)(kt*64 + row)*128 + sg2;
            ushort* dst = Kt + row*136 + sg2;
            #pragma unroll
            for (int i=0;i<4;++i) *(int4*)(dst + i*8) = *(const int4*)(src + i*8);
        }
        {   // V^T tile: 128 d x 64 k
            int row = t >> 1, sg2 = (t & 1)*32;
            const ushort* src = vg + (size_t)row*SS + kt*64 + sg2;
            ushort* dst = Vt + row*72 + sg2;
            #pragma unroll
            for (int i=0;i<4;++i) *(int4*)(dst + i*8) = *(const int4*)(src + i*8);
        }
        int mk = mp[kt*64 + lane];
        __syncthreads();
        // ---- S^T = K · Q~^T
        f32x16 S0, S1;
        #pragma unroll
        for (int r=0;r<16;++r){ S0[r]=0.f; S1[r]=0.f; }
        #pragma unroll
        for (int ds=0; ds<8; ++ds){
            bf16x8 k0 = *(const bf16x8*)(Kt + ln*136 + ds*16 + hi*8);
            bf16x8 k1 = *(const bf16x8*)(Kt + (32+ln)*136 + ds*16 + hi*8);
            S0 = MFMA32(k0, qf[ds], S0);
            S1 = MFMA32(k1, qf[ds], S1);
        }
        unsigned long long bal = __ballot(mk != 0);
        if (bal != ~0ull){
            #pragma unroll
            for (int r=0;r<16;++r){
                int row0 = ((r>>2)<<3) + (hi<<2) + (r&3);
                if (__shfl(mk, row0) == 0)      S0[r] = -1e30f;
                if (__shfl(mk, 32 + row0) == 0) S1[r] = -1e30f;
            }
        }
        float rmax = -1e30f;
        #pragma unroll
        for (int r=0;r<16;++r){ rmax = fmaxf(rmax, S0[r]); rmax = fmaxf(rmax, S1[r]); }
        rmax = fmaxf(rmax, __shfl_xor(rmax, 32));
        float mn = fmaxf(fmaxf(m, rmax), -1e20f);
        float alpha = __expf(m - mn);
        float rs = 0.f;
        #pragma unroll
        for (int r=0;r<16;++r){
            S0[r] = __expf(S0[r] - mn); rs += S0[r];
            S1[r] = __expf(S1[r] - mn); rs += S1[r];
        }
        rs += __shfl_xor(rs, 32);
        l = l*alpha + rs; m = mn;
        if (__ballot(alpha == 1.0f) != ~0ull){
            #pragma unroll
            for (int d=0; d<4; ++d){
                #pragma unroll
                for (int r=0;r<16;++r) O[d][r] *= alpha;
            }
        }
        #pragma unroll
        for (int m2=0; m2<2; ++m2){
            #pragma unroll
            for (int T=0; T<2; ++T){
                const f32x16& P = m2 ? S1 : S0;
                unsigned A0 = pkbf(P[8*T+0], P[8*T+1]);
                unsigned A1 = pkbf(P[8*T+2], P[8*T+3]);
                unsigned B0 = pkbf(P[8*T+4], P[8*T+5]);
                unsigned B1 = pkbf(P[8*T+6], P[8*T+7]);
                unsigned X0 = hi ? A0 : B0, X1 = hi ? A1 : B1;
                unsigned Y0 = (unsigned)__shfl_xor((int)X0, 32);
                unsigned Y1 = (unsigned)__shfl_xor((int)X1, 32);
                union { bf16x8 v; unsigned u[4]; } pf;
                pf.u[0] = hi ? Y0 : A0;
                pf.u[1] = hi ? Y1 : A1;
                pf.u[2] = hi ? B0 : Y0;
                pf.u[3] = hi ? B1 : Y1;
                int kc0 = m2*32 + T*16 + hi*8;
                #pragma unroll
                for (int db=0; db<4; ++db){
                    bf16x8 vf = *(const bf16x8*)(Vt + (db*32 + ln)*72 + kc0);
                    O[db] = MFMA32(vf, pf.v, O[db]);
                }
            }
        }
    }
    // ---- epilogue: normalize, pack bf16, write ctx in proj-A-fragment layout
    // ctxf[mt][ds][hi_p][ln][8]: element j = ctx[m = mt*32+ln][f = ds*16+hi_p*8+j]
    float inv = 1.f / l;
    int h = bh & 15;
    int mt = b*64 + qt*4 + w;
    int4* cf = (int4*)ctxf;
    #pragma unroll
    for (int db=0; db<4; ++db){
        unsigned u[4][2];
        #pragma unroll
        for (int g2=0; g2<4; ++g2){
            u[g2][0] = pkbf(O[db][g2*4+0]*inv, O[db][g2*4+1]*inv);
            u[g2][1] = pkbf(O[db][g2*4+2]*inv, O[db][g2*4+3]*inv);
        }
        #pragma unroll
        for (int gg=0; gg<2; ++gg){
            int g2s = hi*2 + gg;       // combo this lane stores
            int g2p = g2s ^ 2;         // combo the partner stores (what I send)
            unsigned r0 = (unsigned)__shfl_xor((int)u[g2p][0], 32);
            unsigned r1 = (unsigned)__shfl_xor((int)u[g2p][1], 32);
            int4 frag;
            frag.x = (int)(hi ? r0 : u[g2s][0]);
            frag.y = (int)(hi ? r1 : u[g2s][1]);
            frag.z = (int)(hi ? u[g2s][0] : r0);
            frag.w = (int)(hi ? u[g2s][1] : r1);
            int ds = h*8 + db*2 + hi;
            cf[ ((size_t)(mt*128 + ds)*2 + gg)*32 + ln ] = frag;
        }
    }
}

// ---------------- projection: zero-LDS streaming MFMA ----------------
// wave (mt=blockIdx, ct=w): C-tile 32 rows x 32 cols, K=2048 in 128 steps
__global__ __launch_bounds__(256) void proj_kernel(const ushort* __restrict__ ctxf,
                                                   const ushort* __restrict__ wfrag,
                                                   const float* __restrict__ bo,
                                                   float* __restrict__ out){
    int t = threadIdx.x, w = t >> 6, lane = t & 63;
    int hi = lane >> 5, ln = lane & 31;
    int mt = blockIdx.x, ct = w;
    const int4* A = (const int4*)ctxf + (size_t)mt*8192 + lane;
    const int4* B = (const int4*)wfrag + (size_t)ct*8192 + lane;
    f32x16 acc;
    #pragma unroll
    for (int r=0;r<16;++r) acc[r] = 0.f;
    #pragma unroll 8
    for (int ds=0; ds<128; ++ds){
        bf16x8 a = *(const bf16x8*)(A + (size_t)ds*64);
        bf16x8 b = *(const bf16x8*)(B + (size_t)ds*64);
        acc = MFMA32(a, b, acc);
    }
    float bias = bo[ct*32 + ln];
    float* op = out + (size_t)(mt*32)*128 + ct*32 + ln;
    #pragma unroll
    for (int r=0;r<16;++r){
        int row = (r&3) + 8*(r>>2) + 4*hi;
        op[(size_t)row*128] = acc[r] + bias;
    }
}

extern "C" void kernel_launch(void* const* d_in, const int* in_sizes, int n_in,
                              void* d_out, int out_size, void* d_ws, size_t ws_size,
                              hipStream_t stream){
    const float* states = (const float*)d_in[0];
    const int*   mask   = (const int*)d_in[1];
    const float* qp     = (const float*)d_in[2];
    const float* kp     = (const float*)d_in[3];
    const float* vp     = (const float*)d_in[4];
    const float* W      = (const float*)d_in[5];
    const float* bo     = (const float*)d_in[6];
    float* out = (float*)d_out;
    char* wsb = (char*)d_ws;
    // ws (bytes): gates f32 16K | qb u16 16.77M | kb | vt | ctxf | wfrag 512K
    float*  gates = (float*)wsb;
    ushort* qb   = (ushort*)(wsb + 16384);
    ushort* kb   = (ushort*)(wsb + 16384 + 1u*16777216);
    ushort* vtb  = (ushort*)(wsb + 16384 + 2u*16777216);
    ushort* ctxf = (ushort*)(wsb + 16384 + 3u*16777216);
    ushort* wfrag= (ushort*)(wsb + 16384 + 4u*16777216);
    hipLaunchKernelGGL(prep_kernel, dim3(129), dim3(256), 0, stream, qp, kp, vp, W, gates, wfrag);
    hipLaunchKernelGGL(qkv_kernel, dim3(1024), dim3(256), 0, stream, states, gates, qb, kb, vtb);
    hipLaunchKernelGGL(flash_kernel, dim3(512), dim3(256), 0, stream, qb, kb, vtb, mask, ctxf);
    hipLaunchKernelGGL(proj_kernel, dim3(128), dim3(256), 0, stream, ctxf, wfrag, bo, out);
}